// Round 9
// baseline (585.910 us; speedup 1.0000x reference)
//
#include <hip/hip_runtime.h>
#include <hip/hip_bf16.h>

// Pipeline (fp32):
//  1. counts[i] = #in-edges (int hist); dis[i] = rsqrt(counts+1)
//  2. CSR by dst: blocksum -> chunk scan -> scanwrite (rowStart, cursor) -> place (eidx)
//  3. A = x @ W1
//  4. B[d,:] = dis[d]^2*A[d,:] + sum_{e: dst=d} dis[src]*dis[d]*A[src,:]   (gather, no atomics)
//  5. A = relu(B + b1) @ W2
//  6. B = gather(A)
//  7. Z[m] = segment-mean relu(B + b2)  (batch sorted)
//  8. out = Z @ Wf + bf
//
// GEMM v2: 64x128 tile, per-thread 8 rows x 4 cols (32 FMA/k), X staged
// TRANSPOSED in LDS (Xs_T[col][row], pad 68 for 16B alignment) so the k-th
// column read is wave-uniform broadcast: 3 ds_read_b128 per 32 FMA.

#define GEMM_ROWS 64
#define XPAD 68          // row-stride of transposed X tile (floats); 68*4B%16==0
#define CHUNK 1024       // elems per scan chunk (256 threads x 4)

__global__ __launch_bounds__(256)
void k_hist(const int* __restrict__ dst, int* __restrict__ counts, int E) {
    int i = blockIdx.x * 256 + threadIdx.x;
    if (i < E) atomicAdd(&counts[dst[i]], 1);
}

__global__ __launch_bounds__(256)
void k_dis(const int* __restrict__ counts, float* __restrict__ dis, int N) {
    int i = blockIdx.x * 256 + threadIdx.x;
    if (i < N) dis[i] = rsqrtf((float)counts[i] + 1.0f);   // +1 self loop
}

__global__ __launch_bounds__(256)
void k_blocksum(const int* __restrict__ counts, int* __restrict__ chunkSum, int N) {
    __shared__ int s[256];
    int b = blockIdx.x, t = threadIdx.x;
    int base = b * CHUNK + t * 4;
    int p = 0;
    #pragma unroll
    for (int i = 0; i < 4; ++i) if (base + i < N) p += counts[base + i];
    s[t] = p; __syncthreads();
    for (int off = 128; off > 0; off >>= 1) {
        if (t < off) s[t] += s[t + off];
        __syncthreads();
    }
    if (t == 0) chunkSum[b] = s[0];
}

// single block: exclusive scan of chunk sums (nChunks <= 256); also rowStart[N] = E
__global__ __launch_bounds__(256)
void k_scanchunks(const int* __restrict__ chunkSum, int* __restrict__ chunkOff,
                  int* __restrict__ rowStart, int nChunks, int N, int E) {
    __shared__ int s[256];
    int t = threadIdx.x;
    int v = (t < nChunks) ? chunkSum[t] : 0;
    s[t] = v; __syncthreads();
    for (int off = 1; off < 256; off <<= 1) {
        int u = (t >= off) ? s[t - off] : 0;
        __syncthreads();
        s[t] += u;
        __syncthreads();
    }
    if (t < nChunks) chunkOff[t] = s[t] - v;   // exclusive
    if (t == 0) rowStart[N] = E;
}

// NOTE: counts and cursor may ALIAS (each thread reads its 4 counts into
// registers before writing cursor at the same addresses) -> no __restrict__.
__global__ __launch_bounds__(256)
void k_scanwrite(const int* counts, const int* __restrict__ chunkOff,
                 int* __restrict__ rowStart, int* cursor, int N) {
    __shared__ int s[256];
    int b = blockIdx.x, t = threadIdx.x;
    int base = b * CHUNK + t * 4;
    int c[4]; int p = 0;
    #pragma unroll
    for (int i = 0; i < 4; ++i) { c[i] = (base + i < N) ? counts[base + i] : 0; p += c[i]; }
    s[t] = p; __syncthreads();
    for (int off = 1; off < 256; off <<= 1) {
        int u = (t >= off) ? s[t - off] : 0;
        __syncthreads();
        s[t] += u;
        __syncthreads();
    }
    int off = chunkOff[b] + s[t] - p;   // exclusive prefix for this thread
    #pragma unroll
    for (int i = 0; i < 4; ++i) {
        if (base + i < N) { rowStart[base + i] = off; cursor[base + i] = off; off += c[i]; }
    }
}

__global__ __launch_bounds__(256)
void k_place(const int* __restrict__ src, const int* __restrict__ dst,
             int* __restrict__ cursor, int* __restrict__ eidx, int E) {
    int e = blockIdx.x * 256 + threadIdx.x;
    if (e >= E) return;
    int d = dst[e];
    int pos = atomicAdd(&cursor[d], 1);
    eidx[pos] = src[e];
}

// one 64-lane wave per node; lane holds 2 floats (128 cols). No atomics.
__global__ __launch_bounds__(256)
void k_gather(const float* __restrict__ A, const float* __restrict__ dis,
              const int* __restrict__ rowStart, const int* __restrict__ eidx,
              float* __restrict__ B, int N) {
    int d = blockIdx.x * 4 + (threadIdx.x >> 6);
    if (d >= N) return;
    int lane = threadIdx.x & 63;
    float dd = dis[d];
    int beg = rowStart[d], end = rowStart[d + 1];
    float2 v = *(const float2*)&A[(size_t)d * 128 + lane * 2];
    float2 acc = { v.x * dd * dd, v.y * dd * dd };      // self loop
    for (int j = beg; j < end; ++j) {
        int s = eidx[j];                                 // wave-uniform
        float nrm = dd * dis[s];
        float2 u = *(const float2*)&A[(size_t)s * 128 + lane * 2];
        acc.x += nrm * u.x;
        acc.y += nrm * u.y;
    }
    *(float2*)&B[(size_t)d * 128 + lane * 2] = acc;
}

// Y[r,:] = act(X[r,:]) @ W (+ bout), act = relu(x + bin) if RELU_IN.
// 64x128 tile; tx=tid&31 -> cols tx*4..+3, ty=tid>>5 -> rows ty*8..+7.
// Per k: 1 b128 W read (lane-contiguous) + 2 b128 X reads (wave-uniform
// broadcast from transposed tile) feeding 32 FMAs.
template<bool RELU_IN, bool OUT_BIAS>
__global__ __launch_bounds__(256)
void k_gemm128(const float* __restrict__ X, const float* __restrict__ W,
               const float* __restrict__ bin, const float* __restrict__ bout,
               float* __restrict__ Y, int nrows) {
    __shared__ float Xs[128 * XPAD];   // transposed: Xs[c*XPAD + row]
    __shared__ float Ws[32 * 128];     // K-chunk of W, row-major
    const int tid = threadIdx.x;
    const int row0 = blockIdx.x * GEMM_ROWS;

    // stage X tile transposed (with fused bias+relu on input)
    #pragma unroll
    for (int i = 0; i < 8; ++i) {
        int idx = tid + 256 * i;        // 0..2047 float4 slots (64 rows x 32)
        int row = idx >> 5;
        int c4  = idx & 31;
        int gr  = row0 + row;
        float4 v = {0.f, 0.f, 0.f, 0.f};
        if (gr < nrows) v = *(const float4*)&X[(size_t)gr * 128 + c4 * 4];
        if (RELU_IN) {
            float4 b = *(const float4*)&bin[c4 * 4];
            v.x = fmaxf(v.x + b.x, 0.f);
            v.y = fmaxf(v.y + b.y, 0.f);
            v.z = fmaxf(v.z + b.z, 0.f);
            v.w = fmaxf(v.w + b.w, 0.f);
        }
        Xs[(c4 * 4 + 0) * XPAD + row] = v.x;
        Xs[(c4 * 4 + 1) * XPAD + row] = v.y;
        Xs[(c4 * 4 + 2) * XPAD + row] = v.z;
        Xs[(c4 * 4 + 3) * XPAD + row] = v.w;
    }

    const int tx = tid & 31;    // cols tx*4..tx*4+3
    const int ty = tid >> 5;    // rows ty*8..ty*8+7
    float4 acc[8];
    #pragma unroll
    for (int r = 0; r < 8; ++r) acc[r] = {0.f, 0.f, 0.f, 0.f};

    const float4* Ws4 = (const float4*)Ws;

    for (int kk = 0; kk < 128; kk += 32) {
        __syncthreads();        // Xs ready (first) / Ws reuse safe (later)
        // stage W chunk [kk..kk+32) x 128 : 4096 floats = 1024 float4
        const float4* Wv = (const float4*)(W + kk * 128);
        float4* Wsv = (float4*)Ws;
        #pragma unroll
        for (int i = 0; i < 4; ++i) Wsv[tid + 256 * i] = Wv[tid + 256 * i];
        __syncthreads();

        #pragma unroll 8
        for (int k = 0; k < 32; ++k) {
            int c = kk + k;
            float4 w  = Ws4[k * 32 + tx];
            float4 x0 = *(const float4*)&Xs[c * XPAD + ty * 8];
            float4 x1 = *(const float4*)&Xs[c * XPAD + ty * 8 + 4];
            acc[0].x += x0.x * w.x; acc[0].y += x0.x * w.y; acc[0].z += x0.x * w.z; acc[0].w += x0.x * w.w;
            acc[1].x += x0.y * w.x; acc[1].y += x0.y * w.y; acc[1].z += x0.y * w.z; acc[1].w += x0.y * w.w;
            acc[2].x += x0.z * w.x; acc[2].y += x0.z * w.y; acc[2].z += x0.z * w.z; acc[2].w += x0.z * w.w;
            acc[3].x += x0.w * w.x; acc[3].y += x0.w * w.y; acc[3].z += x0.w * w.z; acc[3].w += x0.w * w.w;
            acc[4].x += x1.x * w.x; acc[4].y += x1.x * w.y; acc[4].z += x1.x * w.z; acc[4].w += x1.x * w.w;
            acc[5].x += x1.y * w.x; acc[5].y += x1.y * w.y; acc[5].z += x1.y * w.z; acc[5].w += x1.y * w.w;
            acc[6].x += x1.z * w.x; acc[6].y += x1.z * w.y; acc[6].z += x1.z * w.z; acc[6].w += x1.z * w.w;
            acc[7].x += x1.w * w.x; acc[7].y += x1.w * w.y; acc[7].z += x1.w * w.z; acc[7].w += x1.w * w.w;
        }
    }

    #pragma unroll
    for (int r = 0; r < 8; ++r) {
        int gr = row0 + ty * 8 + r;
        if (gr < nrows) {
            float4 o = acc[r];
            if (OUT_BIAS) {
                float4 b = *(const float4*)&bout[tx * 4];
                o.x += b.x; o.y += b.y; o.z += b.z; o.w += b.w;
            }
            *(float4*)&Y[(size_t)gr * 128 + tx * 4] = o;
        }
    }
}

// segment mean of relu(H + b); batch sorted ascending. one block per segment.
__global__ __launch_bounds__(128)
void k_pool(const float* __restrict__ H, const float* __restrict__ b,
            const int* __restrict__ batch, float* __restrict__ Z, int N) {
    int m = blockIdx.x;
    int lo = 0, hi = N;
    while (lo < hi) { int mid = (lo + hi) >> 1; if (batch[mid] < m) lo = mid + 1; else hi = mid; }
    int start = lo;
    hi = N;
    while (lo < hi) { int mid = (lo + hi) >> 1; if (batch[mid] < m + 1) lo = mid + 1; else hi = mid; }
    int end = lo;

    int j = threadIdx.x;
    float bj = b[j];
    float acc = 0.f;
    for (int i = start; i < end; ++i)
        acc += fmaxf(H[(size_t)i * 128 + j] + bj, 0.f);
    float cnt = (float)(end - start);
    Z[(size_t)m * 128 + j] = acc / fmaxf(cnt, 1.f);
}

extern "C" void kernel_launch(void* const* d_in, const int* in_sizes, int n_in,
                              void* d_out, int out_size, void* d_ws, size_t ws_size,
                              hipStream_t stream) {
    const float* x   = (const float*)d_in[0];
    const int*   ei  = (const int*)d_in[1];
    const int*   bat = (const int*)d_in[2];
    const float* W1  = (const float*)d_in[3];
    const float* b1  = (const float*)d_in[4];
    const float* W2  = (const float*)d_in[5];
    const float* b2  = (const float*)d_in[6];
    const float* Wf  = (const float*)d_in[7];
    const float* bf  = (const float*)d_in[8];
    float* out = (float*)d_out;

    const int N = in_sizes[0] / 128;
    const int E = in_sizes[1] / 2;
    const int M = out_size / 128;
    const int* src = ei;
    const int* dst = ei + E;

    // workspace layout (16B-aligned chunks)
    char* ws = (char*)d_ws;
    const size_t feat_bytes = (size_t)N * 128 * sizeof(float);
    size_t off = 0;
    float* A        = (float*)(ws + off); off += feat_bytes;
    float* B        = (float*)(ws + off); off += feat_bytes;
    float* dis      = (float*)(ws + off); off += ((size_t)N * 4 + 15) & ~15ull;
    int*   counts   = (int*)  (ws + off); off += ((size_t)N * 4 + 15) & ~15ull;   // reused as cursor
    int*   rowStart = (int*)  (ws + off); off += ((size_t)(N + 1) * 4 + 15) & ~15ull;
    int*   eidx     = (int*)  (ws + off); off += ((size_t)E * 4 + 15) & ~15ull;
    int*   chunkSum = (int*)  (ws + off); off += 256 * 4;
    int*   chunkOff = (int*)  (ws + off); off += 256 * 4;
    float* Z        = A;   // A is dead after the last gather; pool reads only B

    const int nChunks = (N + CHUNK - 1) / CHUNK;          // 196 for N=200k (<=256)
    const int gemm_blocks = (N + GEMM_ROWS - 1) / GEMM_ROWS;

    // 1. histogram + dis
    hipMemsetAsync(counts, 0, (size_t)N * sizeof(int), stream);
    k_hist<<<(E + 255) / 256, 256, 0, stream>>>(dst, counts, E);
    k_dis<<<(N + 255) / 256, 256, 0, stream>>>(counts, dis, N);

    // 2. CSR build (rowStart, cursor=counts alias, eidx)
    k_blocksum<<<nChunks, 256, 0, stream>>>(counts, chunkSum, N);
    k_scanchunks<<<1, 256, 0, stream>>>(chunkSum, chunkOff, rowStart, nChunks, N, E);
    k_scanwrite<<<nChunks, 256, 0, stream>>>(counts, chunkOff, rowStart, counts, N);
    k_place<<<(E + 255) / 256, 256, 0, stream>>>(src, dst, counts, eidx, E);

    // 3. A = x @ W1
    k_gemm128<false, false><<<gemm_blocks, 256, 0, stream>>>(x, W1, nullptr, nullptr, A, N);

    // 4. B = gather(A)
    k_gather<<<(N + 3) / 4, 256, 0, stream>>>(A, dis, rowStart, eidx, B, N);

    // 5. A = relu(B + b1) @ W2
    k_gemm128<true, false><<<gemm_blocks, 256, 0, stream>>>(B, W2, b1, nullptr, A, N);

    // 6. B = gather(A)
    k_gather<<<(N + 3) / 4, 256, 0, stream>>>(A, dis, rowStart, eidx, B, N);

    // 7. Z = segment-mean(relu(B + b2))
    k_pool<<<M, 128, 0, stream>>>(B, b2, bat, Z, N);

    // 8. out = Z @ Wf + bf
    k_gemm128<false, true><<<(M + GEMM_ROWS - 1) / GEMM_ROWS, 256, 0, stream>>>(
        Z, Wf, nullptr, bf, out, M);
}

// Round 10
// 443.942 us; speedup vs baseline: 1.3198x; 1.3198x over previous
//
#include <hip/hip_runtime.h>
#include <hip/hip_bf16.h>

// Pipeline (bf16 storage, fp32 accumulate):
//  1. counts = in-degree hist; dis = rsqrt(deg+1)
//  2. CSR by dst (blocksum/scan/scanwrite/place)
//  3. Wt1/Wt2 = transpose(W1/W2) cast bf16  [col][k]
//  4. A(bf16) = x @ W1                      (MFMA 16x16x32 bf16)
//  5. B(bf16) = gather(A)                   (fp32 accum)
//  6. A(bf16) = relu(B + b1) @ W2           (MFMA)
//  7. B(bf16) = gather(A)
//  8. Z(f32)  = segment-mean relu(B + b2)
//  9. out = Z @ Wf + bf                     (fp32 VALU, tiny)

typedef __attribute__((ext_vector_type(8))) short short8;
typedef __attribute__((ext_vector_type(4))) float f32x4;
typedef __attribute__((ext_vector_type(4))) unsigned short ushort4v;

#define XPADB 136     // LDS row stride in bf16 elems (128+8); 272B, 16B-aligned, bank-safe
#define CHUNK 1024

static __device__ __forceinline__ unsigned short f2b(float f) {   // RNE f32->bf16
    unsigned u = __builtin_bit_cast(unsigned, f);
    return (unsigned short)((u + 0x7FFFu + ((u >> 16) & 1u)) >> 16);
}
static __device__ __forceinline__ float b2f(unsigned short h) {
    unsigned u = ((unsigned)h) << 16;
    return __builtin_bit_cast(float, u);
}

__global__ __launch_bounds__(256)
void k_hist(const int* __restrict__ dst, int* __restrict__ counts, int E) {
    int i = blockIdx.x * 256 + threadIdx.x;
    if (i < E) atomicAdd(&counts[dst[i]], 1);
}

__global__ __launch_bounds__(256)
void k_dis(const int* __restrict__ counts, float* __restrict__ dis, int N) {
    int i = blockIdx.x * 256 + threadIdx.x;
    if (i < N) dis[i] = rsqrtf((float)counts[i] + 1.0f);
}

__global__ __launch_bounds__(256)
void k_blocksum(const int* __restrict__ counts, int* __restrict__ chunkSum, int N) {
    __shared__ int s[256];
    int b = blockIdx.x, t = threadIdx.x;
    int base = b * CHUNK + t * 4;
    int p = 0;
    #pragma unroll
    for (int i = 0; i < 4; ++i) if (base + i < N) p += counts[base + i];
    s[t] = p; __syncthreads();
    for (int off = 128; off > 0; off >>= 1) {
        if (t < off) s[t] += s[t + off];
        __syncthreads();
    }
    if (t == 0) chunkSum[b] = s[0];
}

__global__ __launch_bounds__(256)
void k_scanchunks(const int* __restrict__ chunkSum, int* __restrict__ chunkOff,
                  int* __restrict__ rowStart, int nChunks, int N, int E) {
    __shared__ int s[256];
    int t = threadIdx.x;
    int v = (t < nChunks) ? chunkSum[t] : 0;
    s[t] = v; __syncthreads();
    for (int off = 1; off < 256; off <<= 1) {
        int u = (t >= off) ? s[t - off] : 0;
        __syncthreads();
        s[t] += u;
        __syncthreads();
    }
    if (t < nChunks) chunkOff[t] = s[t] - v;
    if (t == 0) rowStart[N] = E;
}

// counts/cursor may alias (read-before-write per thread) -> no __restrict__
__global__ __launch_bounds__(256)
void k_scanwrite(const int* counts, const int* __restrict__ chunkOff,
                 int* __restrict__ rowStart, int* cursor, int N) {
    __shared__ int s[256];
    int b = blockIdx.x, t = threadIdx.x;
    int base = b * CHUNK + t * 4;
    int c[4]; int p = 0;
    #pragma unroll
    for (int i = 0; i < 4; ++i) { c[i] = (base + i < N) ? counts[base + i] : 0; p += c[i]; }
    s[t] = p; __syncthreads();
    for (int off = 1; off < 256; off <<= 1) {
        int u = (t >= off) ? s[t - off] : 0;
        __syncthreads();
        s[t] += u;
        __syncthreads();
    }
    int off = chunkOff[b] + s[t] - p;
    #pragma unroll
    for (int i = 0; i < 4; ++i) {
        if (base + i < N) { rowStart[base + i] = off; cursor[base + i] = off; off += c[i]; }
    }
}

__global__ __launch_bounds__(256)
void k_place(const int* __restrict__ src, const int* __restrict__ dst,
             int* __restrict__ cursor, int* __restrict__ eidx, int E) {
    int e = blockIdx.x * 256 + threadIdx.x;
    if (e >= E) return;
    int d = dst[e];
    int pos = atomicAdd(&cursor[d], 1);
    eidx[pos] = src[e];
}

// Wt[c*128 + k] = bf16(W[k*128 + c]); grid 64 blocks per W
__global__ __launch_bounds__(256)
void k_prepw(const float* __restrict__ W, unsigned short* __restrict__ Wt) {
    int i = blockIdx.x * 256 + threadIdx.x;
    if (i < 128 * 128) {
        int k = i >> 7, c = i & 127;
        Wt[c * 128 + k] = f2b(W[i]);
    }
}

// MFMA GEMM: Y(bf16)[64x128 tile] = act(X) @ W.  Wt is bf16 [col][k].
// 4 waves; wave w -> rows w*16..+15, 8 col-tiles of 16. K=128 in 4 chunks.
// A/B frags both use slot->k map k=8*(lane>>4)+j (consistent => order-invariant).
template<bool BF16_IN, bool RELU_IN>
__global__ __launch_bounds__(256)
void k_gemm_mfma(const void* __restrict__ Xv, const unsigned short* __restrict__ Wt,
                 const float* __restrict__ bin, unsigned short* __restrict__ Y,
                 int nrows) {
    __shared__ unsigned short Xs[64 * XPADB];    // [row][k]
    __shared__ unsigned short Ws[128 * XPADB];   // [col][k]
    const int tid = threadIdx.x;
    const int row0 = blockIdx.x * 64;

    // stage Wt -> Ws (2048 16B-chunks)
    #pragma unroll
    for (int i = 0; i < 8; ++i) {
        int q = tid + 256 * i;
        int col = q >> 4, k8 = q & 15;
        *(short8*)&Ws[col * XPADB + k8 * 8] = *(const short8*)&Wt[col * 128 + k8 * 8];
    }

    // stage X -> Xs (bf16, fused bias+relu)
    if (BF16_IN) {
        const unsigned short* X = (const unsigned short*)Xv;
        #pragma unroll
        for (int i = 0; i < 4; ++i) {
            int q = tid + 256 * i;              // 64 rows x 16 chunks
            int row = q >> 4, k8 = q & 15;
            int gr = row0 + row;
            unsigned short v[8];
            if (gr < nrows) {
                short8 raw = *(const short8*)&X[(size_t)gr * 128 + k8 * 8];
                #pragma unroll
                for (int e = 0; e < 8; ++e) {
                    float f = b2f((unsigned short)raw[e]);
                    if (RELU_IN) f = fmaxf(f + bin[k8 * 8 + e], 0.f);
                    v[e] = f2b(f);
                }
            } else {
                #pragma unroll
                for (int e = 0; e < 8; ++e) v[e] = 0;
            }
            *(ushort4v*)&Xs[row * XPADB + k8 * 8]     = (ushort4v){v[0], v[1], v[2], v[3]};
            *(ushort4v*)&Xs[row * XPADB + k8 * 8 + 4] = (ushort4v){v[4], v[5], v[6], v[7]};
        }
    } else {
        const float* X = (const float*)Xv;
        #pragma unroll
        for (int i = 0; i < 8; ++i) {
            int q = tid + 256 * i;              // 64 rows x 32 float4-chunks
            int row = q >> 5, c4 = q & 31;
            int gr = row0 + row;
            float4 f = {0.f, 0.f, 0.f, 0.f};
            if (gr < nrows) f = *(const float4*)((const float*)X + (size_t)gr * 128 + c4 * 4);
            if (RELU_IN) {
                f.x = fmaxf(f.x + bin[c4 * 4 + 0], 0.f);
                f.y = fmaxf(f.y + bin[c4 * 4 + 1], 0.f);
                f.z = fmaxf(f.z + bin[c4 * 4 + 2], 0.f);
                f.w = fmaxf(f.w + bin[c4 * 4 + 3], 0.f);
            }
            *(ushort4v*)&Xs[row * XPADB + c4 * 4] =
                (ushort4v){f2b(f.x), f2b(f.y), f2b(f.z), f2b(f.w)};
        }
    }
    __syncthreads();

    const int l = tid & 63;
    const int w = tid >> 6;
    const int r = l & 15;
    const int g = l >> 4;

    f32x4 acc[8];
    #pragma unroll
    for (int n = 0; n < 8; ++n) acc[n] = (f32x4){0.f, 0.f, 0.f, 0.f};

    #pragma unroll
    for (int kk = 0; kk < 4; ++kk) {
        short8 af = *(const short8*)&Xs[(w * 16 + r) * XPADB + kk * 32 + g * 8];
        #pragma unroll
        for (int n = 0; n < 8; ++n) {
            short8 bfr = *(const short8*)&Ws[(n * 16 + r) * XPADB + kk * 32 + g * 8];
            acc[n] = __builtin_amdgcn_mfma_f32_16x16x32_bf16(af, bfr, acc[n], 0, 0, 0);
        }
    }

    // C/D: col = lane&15, row = (lane>>4)*4 + j   [HW-verified m89]
    #pragma unroll
    for (int n = 0; n < 8; ++n) {
        #pragma unroll
        for (int j = 0; j < 4; ++j) {
            int grow = row0 + w * 16 + g * 4 + j;
            if (grow < nrows)
                Y[(size_t)grow * 128 + n * 16 + r] = f2b(acc[n][j]);
        }
    }
}

// one 64-lane wave per node; lane holds 2 cols. fp32 accum, bf16 in/out.
__global__ __launch_bounds__(256)
void k_gather(const unsigned short* __restrict__ A, const float* __restrict__ dis,
              const int* __restrict__ rowStart, const int* __restrict__ eidx,
              unsigned short* __restrict__ B, int N) {
    int d = blockIdx.x * 4 + (threadIdx.x >> 6);
    if (d >= N) return;
    int lane = threadIdx.x & 63;
    float dd = dis[d];
    int beg = rowStart[d], end = rowStart[d + 1];
    unsigned sv = *(const unsigned*)&A[(size_t)d * 128 + lane * 2];
    float acc0 = dd * dd * b2f((unsigned short)(sv & 0xFFFF));
    float acc1 = dd * dd * b2f((unsigned short)(sv >> 16));
    for (int j = beg; j < end; ++j) {
        int s = eidx[j];                       // wave-uniform
        float nrm = dd * dis[s];
        unsigned uu = *(const unsigned*)&A[(size_t)s * 128 + lane * 2];
        acc0 += nrm * b2f((unsigned short)(uu & 0xFFFF));
        acc1 += nrm * b2f((unsigned short)(uu >> 16));
    }
    *(unsigned*)&B[(size_t)d * 128 + lane * 2] =
        (unsigned)f2b(acc0) | ((unsigned)f2b(acc1) << 16);
}

// segment mean of relu(H + b); batch sorted. one block per segment. H bf16.
__global__ __launch_bounds__(128)
void k_pool(const unsigned short* __restrict__ H, const float* __restrict__ b,
            const int* __restrict__ batch, float* __restrict__ Z, int N) {
    int m = blockIdx.x;
    int lo = 0, hi = N;
    while (lo < hi) { int mid = (lo + hi) >> 1; if (batch[mid] < m) lo = mid + 1; else hi = mid; }
    int start = lo;
    hi = N;
    while (lo < hi) { int mid = (lo + hi) >> 1; if (batch[mid] < m + 1) lo = mid + 1; else hi = mid; }
    int end = lo;

    int j = threadIdx.x;
    float bj = b[j];
    float acc = 0.f;
    for (int i = start; i < end; ++i)
        acc += fmaxf(b2f(H[(size_t)i * 128 + j]) + bj, 0.f);
    float cnt = (float)(end - start);
    Z[(size_t)m * 128 + j] = acc / fmaxf(cnt, 1.f);
}

// fp32 VALU GEMM for the tiny head (M=2000). R8 structure, zero conflicts.
__global__ __launch_bounds__(256)
void k_gemm_f32(const float* __restrict__ X, const float* __restrict__ W,
                const float* __restrict__ bout, float* __restrict__ Y, int nrows) {
    __shared__ float Ws[64 * 128];
    __shared__ float Xs[32 * 128];
    const int tid = threadIdx.x;
    const int row0 = blockIdx.x * 32;

    {
        float4* Xsv = (float4*)Xs;
        #pragma unroll
        for (int i = 0; i < 4; ++i) {
            int idx = tid + 256 * i;
            int r = idx >> 5, c4 = idx & 31;
            int gr = row0 + r;
            float4 v = {0.f, 0.f, 0.f, 0.f};
            if (gr < nrows) v = *(const float4*)&X[(size_t)gr * 128 + c4 * 4];
            Xsv[idx] = v;
        }
    }

    const int tx = tid & 31;
    const int ty = tid >> 5;
    float4 acc[4];
    #pragma unroll
    for (int r = 0; r < 4; ++r) acc[r] = {0.f, 0.f, 0.f, 0.f};

    for (int kk = 0; kk < 128; kk += 64) {
        __syncthreads();
        const float4* Wv = (const float4*)(W + kk * 128);
        float4* Wsv = (float4*)Ws;
        #pragma unroll
        for (int i = 0; i < 8; ++i) Wsv[tid + 256 * i] = Wv[tid + 256 * i];
        __syncthreads();

        #pragma unroll 4
        for (int k = 0; k < 64; ++k) {
            float4 wv = *(const float4*)&Ws[k * 128 + tx * 4];
            #pragma unroll
            for (int r = 0; r < 4; ++r) {
                float xv = Xs[(ty + 8 * r) * 128 + kk + k];
                acc[r].x += xv * wv.x;
                acc[r].y += xv * wv.y;
                acc[r].z += xv * wv.z;
                acc[r].w += xv * wv.w;
            }
        }
    }

    #pragma unroll
    for (int r = 0; r < 4; ++r) {
        int gr = row0 + ty + 8 * r;
        if (gr < nrows) {
            float4 o = acc[r];
            float4 b = *(const float4*)&bout[tx * 4];
            o.x += b.x; o.y += b.y; o.z += b.z; o.w += b.w;
            *(float4*)&Y[(size_t)gr * 128 + tx * 4] = o;
        }
    }
}

extern "C" void kernel_launch(void* const* d_in, const int* in_sizes, int n_in,
                              void* d_out, int out_size, void* d_ws, size_t ws_size,
                              hipStream_t stream) {
    const float* x   = (const float*)d_in[0];
    const int*   ei  = (const int*)d_in[1];
    const int*   bat = (const int*)d_in[2];
    const float* W1  = (const float*)d_in[3];
    const float* b1  = (const float*)d_in[4];
    const float* W2  = (const float*)d_in[5];
    const float* b2  = (const float*)d_in[6];
    const float* Wf  = (const float*)d_in[7];
    const float* bf  = (const float*)d_in[8];
    float* out = (float*)d_out;

    const int N = in_sizes[0] / 128;
    const int E = in_sizes[1] / 2;
    const int M = out_size / 128;
    const int* src = ei;
    const int* dst = ei + E;

    char* ws = (char*)d_ws;
    const size_t featb = (size_t)N * 128 * 2;   // bf16 feature plane
    size_t off = 0;
    unsigned short* A   = (unsigned short*)(ws + off); off += (featb + 15) & ~15ull;
    unsigned short* B   = (unsigned short*)(ws + off); off += (featb + 15) & ~15ull;
    float* dis          = (float*)(ws + off); off += (((size_t)N * 4) + 15) & ~15ull;
    int*   counts       = (int*)  (ws + off); off += (((size_t)N * 4) + 15) & ~15ull;
    int*   rowStart     = (int*)  (ws + off); off += (((size_t)(N + 1) * 4) + 15) & ~15ull;
    int*   eidx         = (int*)  (ws + off); off += (((size_t)E * 4) + 15) & ~15ull;
    int*   chunkSum     = (int*)  (ws + off); off += 256 * 4;
    int*   chunkOff     = (int*)  (ws + off); off += 256 * 4;
    unsigned short* Wt1 = (unsigned short*)(ws + off); off += 128 * 128 * 2;
    unsigned short* Wt2 = (unsigned short*)(ws + off); off += 128 * 128 * 2;
    float* Z            = (float*)(ws + off); off += (size_t)M * 128 * 4;

    const int nChunks = (N + CHUNK - 1) / CHUNK;
    const int gemm_blocks = (N + 63) / 64;

    // 1. histogram + dis
    hipMemsetAsync(counts, 0, (size_t)N * sizeof(int), stream);
    k_hist<<<(E + 255) / 256, 256, 0, stream>>>(dst, counts, E);
    k_dis<<<(N + 255) / 256, 256, 0, stream>>>(counts, dis, N);

    // 2. CSR build
    k_blocksum<<<nChunks, 256, 0, stream>>>(counts, chunkSum, N);
    k_scanchunks<<<1, 256, 0, stream>>>(chunkSum, chunkOff, rowStart, nChunks, N, E);
    k_scanwrite<<<nChunks, 256, 0, stream>>>(counts, chunkOff, rowStart, counts, N);
    k_place<<<(E + 255) / 256, 256, 0, stream>>>(src, dst, counts, eidx, E);

    // 3. W transposes (bf16)
    k_prepw<<<64, 256, 0, stream>>>(W1, Wt1);
    k_prepw<<<64, 256, 0, stream>>>(W2, Wt2);

    // 4. A = x @ W1
    k_gemm_mfma<false, false><<<gemm_blocks, 256, 0, stream>>>(x, Wt1, nullptr, A, N);

    // 5. B = gather(A)
    k_gather<<<(N + 3) / 4, 256, 0, stream>>>(A, dis, rowStart, eidx, B, N);

    // 6. A = relu(B + b1) @ W2
    k_gemm_mfma<true, true><<<gemm_blocks, 256, 0, stream>>>(B, Wt2, b1, A, N);

    // 7. B = gather(A)
    k_gather<<<(N + 3) / 4, 256, 0, stream>>>(A, dis, rowStart, eidx, B, N);

    // 8. Z = segment-mean(relu(B + b2))
    k_pool<<<M, 128, 0, stream>>>(B, b2, bat, Z, N);

    // 9. out = Z @ Wf + bf
    k_gemm_f32<<<(M + 31) / 32, 256, 0, stream>>>(Z, Wf, bf, out, M);
}

// Round 11
// 385.215 us; speedup vs baseline: 1.5210x; 1.1525x over previous
//
#include <hip/hip_runtime.h>
#include <hip/hip_bf16.h>

// Pipeline (bf16 storage, fp32 accumulate):
//  1. counts = in-degree hist; dis = rsqrt(deg+1)
//  2. CSR by dst (blocksum/scan/scanwrite/place)
//  3. Wt1/Wt2 = transpose(W1/W2) cast bf16  [col][k]
//  4. A(bf16) = x @ W1                      (MFMA 16x16x32 bf16)
//  5. B(bf16) = gather(A)                   (fp32 accum; 16 lanes/node v2)
//  6. A(bf16) = relu(B + b1) @ W2           (MFMA)
//  7. B(bf16) = gather(A)
//  8. Z(f32)  = segment-mean relu(B + b2)
//  9. out = Z @ Wf + bf                     (fp32 VALU, tiny)

typedef __attribute__((ext_vector_type(8))) short short8;
typedef __attribute__((ext_vector_type(8))) unsigned short ushort8v;
typedef __attribute__((ext_vector_type(4))) unsigned short ushort4v;
typedef __attribute__((ext_vector_type(4))) float f32x4;

#define XPADB 136     // LDS row stride in bf16 elems (128+8); 272B, 16B-aligned, bank-safe
#define CHUNK 1024

static __device__ __forceinline__ unsigned short f2b(float f) {   // RNE f32->bf16
    unsigned u = __builtin_bit_cast(unsigned, f);
    return (unsigned short)((u + 0x7FFFu + ((u >> 16) & 1u)) >> 16);
}
static __device__ __forceinline__ float b2f(unsigned short h) {
    unsigned u = ((unsigned)h) << 16;
    return __builtin_bit_cast(float, u);
}

__global__ __launch_bounds__(256)
void k_hist(const int* __restrict__ dst, int* __restrict__ counts, int E) {
    int i = blockIdx.x * 256 + threadIdx.x;
    if (i < E) atomicAdd(&counts[dst[i]], 1);
}

__global__ __launch_bounds__(256)
void k_dis(const int* __restrict__ counts, float* __restrict__ dis, int N) {
    int i = blockIdx.x * 256 + threadIdx.x;
    if (i < N) dis[i] = rsqrtf((float)counts[i] + 1.0f);
}

__global__ __launch_bounds__(256)
void k_blocksum(const int* __restrict__ counts, int* __restrict__ chunkSum, int N) {
    __shared__ int s[256];
    int b = blockIdx.x, t = threadIdx.x;
    int base = b * CHUNK + t * 4;
    int p = 0;
    #pragma unroll
    for (int i = 0; i < 4; ++i) if (base + i < N) p += counts[base + i];
    s[t] = p; __syncthreads();
    for (int off = 128; off > 0; off >>= 1) {
        if (t < off) s[t] += s[t + off];
        __syncthreads();
    }
    if (t == 0) chunkSum[b] = s[0];
}

__global__ __launch_bounds__(256)
void k_scanchunks(const int* __restrict__ chunkSum, int* __restrict__ chunkOff,
                  int* __restrict__ rowStart, int nChunks, int N, int E) {
    __shared__ int s[256];
    int t = threadIdx.x;
    int v = (t < nChunks) ? chunkSum[t] : 0;
    s[t] = v; __syncthreads();
    for (int off = 1; off < 256; off <<= 1) {
        int u = (t >= off) ? s[t - off] : 0;
        __syncthreads();
        s[t] += u;
        __syncthreads();
    }
    if (t < nChunks) chunkOff[t] = s[t] - v;
    if (t == 0) rowStart[N] = E;
}

// counts/cursor may alias (read-before-write per thread) -> no __restrict__
__global__ __launch_bounds__(256)
void k_scanwrite(const int* counts, const int* __restrict__ chunkOff,
                 int* __restrict__ rowStart, int* cursor, int N) {
    __shared__ int s[256];
    int b = blockIdx.x, t = threadIdx.x;
    int base = b * CHUNK + t * 4;
    int c[4]; int p = 0;
    #pragma unroll
    for (int i = 0; i < 4; ++i) { c[i] = (base + i < N) ? counts[base + i] : 0; p += c[i]; }
    s[t] = p; __syncthreads();
    for (int off = 1; off < 256; off <<= 1) {
        int u = (t >= off) ? s[t - off] : 0;
        __syncthreads();
        s[t] += u;
        __syncthreads();
    }
    int off = chunkOff[b] + s[t] - p;
    #pragma unroll
    for (int i = 0; i < 4; ++i) {
        if (base + i < N) { rowStart[base + i] = off; cursor[base + i] = off; off += c[i]; }
    }
}

__global__ __launch_bounds__(256)
void k_place(const int* __restrict__ src, const int* __restrict__ dst,
             int* __restrict__ cursor, int* __restrict__ eidx, int E) {
    int e = blockIdx.x * 256 + threadIdx.x;
    if (e >= E) return;
    int d = dst[e];
    int pos = atomicAdd(&cursor[d], 1);
    eidx[pos] = src[e];
}

// Wt[c*128 + k] = bf16(W[k*128 + c]); grid 64 blocks per W
__global__ __launch_bounds__(256)
void k_prepw(const float* __restrict__ W, unsigned short* __restrict__ Wt) {
    int i = blockIdx.x * 256 + threadIdx.x;
    if (i < 128 * 128) {
        int k = i >> 7, c = i & 127;
        Wt[c * 128 + k] = f2b(W[i]);
    }
}

// MFMA GEMM: Y(bf16)[64x128 tile] = act(X) @ W.  Wt is bf16 [col][k].
// 4 waves; wave w -> rows w*16..+15, 8 col-tiles of 16. K=128 in 4 chunks.
// A/B frags both use slot->k map k=8*(lane>>4)+j (consistent => order-invariant).
template<bool BF16_IN, bool RELU_IN>
__global__ __launch_bounds__(256)
void k_gemm_mfma(const void* __restrict__ Xv, const unsigned short* __restrict__ Wt,
                 const float* __restrict__ bin, unsigned short* __restrict__ Y,
                 int nrows) {
    __shared__ unsigned short Xs[64 * XPADB];    // [row][k]
    __shared__ unsigned short Ws[128 * XPADB];   // [col][k]
    const int tid = threadIdx.x;
    const int row0 = blockIdx.x * 64;

    // stage Wt -> Ws (2048 16B-chunks)
    #pragma unroll
    for (int i = 0; i < 8; ++i) {
        int q = tid + 256 * i;
        int col = q >> 4, k8 = q & 15;
        *(short8*)&Ws[col * XPADB + k8 * 8] = *(const short8*)&Wt[col * 128 + k8 * 8];
    }

    // stage X -> Xs (bf16, fused bias+relu)
    if (BF16_IN) {
        const unsigned short* X = (const unsigned short*)Xv;
        #pragma unroll
        for (int i = 0; i < 4; ++i) {
            int q = tid + 256 * i;              // 64 rows x 16 chunks
            int row = q >> 4, k8 = q & 15;
            int gr = row0 + row;
            unsigned short v[8];
            if (gr < nrows) {
                short8 raw = *(const short8*)&X[(size_t)gr * 128 + k8 * 8];
                #pragma unroll
                for (int e = 0; e < 8; ++e) {
                    float f = b2f((unsigned short)raw[e]);
                    if (RELU_IN) f = fmaxf(f + bin[k8 * 8 + e], 0.f);
                    v[e] = f2b(f);
                }
            } else {
                #pragma unroll
                for (int e = 0; e < 8; ++e) v[e] = 0;
            }
            *(ushort4v*)&Xs[row * XPADB + k8 * 8]     = (ushort4v){v[0], v[1], v[2], v[3]};
            *(ushort4v*)&Xs[row * XPADB + k8 * 8 + 4] = (ushort4v){v[4], v[5], v[6], v[7]};
        }
    } else {
        const float* X = (const float*)Xv;
        #pragma unroll
        for (int i = 0; i < 8; ++i) {
            int q = tid + 256 * i;              // 64 rows x 32 float4-chunks
            int row = q >> 5, c4 = q & 31;
            int gr = row0 + row;
            float4 f = {0.f, 0.f, 0.f, 0.f};
            if (gr < nrows) f = *(const float4*)((const float*)X + (size_t)gr * 128 + c4 * 4);
            if (RELU_IN) {
                f.x = fmaxf(f.x + bin[c4 * 4 + 0], 0.f);
                f.y = fmaxf(f.y + bin[c4 * 4 + 1], 0.f);
                f.z = fmaxf(f.z + bin[c4 * 4 + 2], 0.f);
                f.w = fmaxf(f.w + bin[c4 * 4 + 3], 0.f);
            }
            *(ushort4v*)&Xs[row * XPADB + c4 * 4] =
                (ushort4v){f2b(f.x), f2b(f.y), f2b(f.z), f2b(f.w)};
        }
    }
    __syncthreads();

    const int l = tid & 63;
    const int w = tid >> 6;
    const int r = l & 15;
    const int g = l >> 4;

    f32x4 acc[8];
    #pragma unroll
    for (int n = 0; n < 8; ++n) acc[n] = (f32x4){0.f, 0.f, 0.f, 0.f};

    #pragma unroll
    for (int kk = 0; kk < 4; ++kk) {
        short8 af = *(const short8*)&Xs[(w * 16 + r) * XPADB + kk * 32 + g * 8];
        #pragma unroll
        for (int n = 0; n < 8; ++n) {
            short8 bfr = *(const short8*)&Ws[(n * 16 + r) * XPADB + kk * 32 + g * 8];
            acc[n] = __builtin_amdgcn_mfma_f32_16x16x32_bf16(af, bfr, acc[n], 0, 0, 0);
        }
    }

    // C/D: col = lane&15, row = (lane>>4)*4 + j   [HW-verified m89]
    #pragma unroll
    for (int n = 0; n < 8; ++n) {
        #pragma unroll
        for (int j = 0; j < 4; ++j) {
            int grow = row0 + w * 16 + g * 4 + j;
            if (grow < nrows)
                Y[(size_t)grow * 128 + n * 16 + r] = f2b(acc[n][j]);
        }
    }
}

// gather v2: 16 lanes per node (lane = 8 bf16 cols, 16B), 4 nodes/wave,
// edge loop unrolled x2 -> up to 8 independent A-row loads in flight per wave.
__global__ __launch_bounds__(256)
void k_gather(const unsigned short* __restrict__ A, const float* __restrict__ dis,
              const int* __restrict__ rowStart, const int* __restrict__ eidx,
              unsigned short* __restrict__ B, int N) {
    int d = blockIdx.x * 16 + (threadIdx.x >> 4);
    if (d >= N) return;
    int lane = threadIdx.x & 15;
    float dd = dis[d];
    int beg = rowStart[d], end = rowStart[d + 1];

    float acc[8];
    {
        ushort8v v = *(const ushort8v*)&A[(size_t)d * 128 + lane * 8];
        float s = dd * dd;                       // self loop
        #pragma unroll
        for (int e = 0; e < 8; ++e) acc[e] = s * b2f((unsigned short)v[e]);
    }
    int j = beg;
    for (; j + 2 <= end; j += 2) {
        int s0 = eidx[j], s1 = eidx[j + 1];
        float n0 = dd * dis[s0], n1 = dd * dis[s1];
        ushort8v u0 = *(const ushort8v*)&A[(size_t)s0 * 128 + lane * 8];
        ushort8v u1 = *(const ushort8v*)&A[(size_t)s1 * 128 + lane * 8];
        #pragma unroll
        for (int e = 0; e < 8; ++e)
            acc[e] += n0 * b2f((unsigned short)u0[e]) + n1 * b2f((unsigned short)u1[e]);
    }
    if (j < end) {
        int s0 = eidx[j];
        float n0 = dd * dis[s0];
        ushort8v u0 = *(const ushort8v*)&A[(size_t)s0 * 128 + lane * 8];
        #pragma unroll
        for (int e = 0; e < 8; ++e) acc[e] += n0 * b2f((unsigned short)u0[e]);
    }
    ushort8v o;
    #pragma unroll
    for (int e = 0; e < 8; ++e) o[e] = f2b(acc[e]);
    *(ushort8v*)&B[(size_t)d * 128 + lane * 8] = o;
}

// segment mean of relu(H + b); batch sorted. one block per segment. H bf16.
__global__ __launch_bounds__(128)
void k_pool(const unsigned short* __restrict__ H, const float* __restrict__ b,
            const int* __restrict__ batch, float* __restrict__ Z, int N) {
    int m = blockIdx.x;
    int lo = 0, hi = N;
    while (lo < hi) { int mid = (lo + hi) >> 1; if (batch[mid] < m) lo = mid + 1; else hi = mid; }
    int start = lo;
    hi = N;
    while (lo < hi) { int mid = (lo + hi) >> 1; if (batch[mid] < m + 1) lo = mid + 1; else hi = mid; }
    int end = lo;

    int j = threadIdx.x;
    float bj = b[j];
    float acc = 0.f;
    for (int i = start; i < end; ++i)
        acc += fmaxf(b2f(H[(size_t)i * 128 + j]) + bj, 0.f);
    float cnt = (float)(end - start);
    Z[(size_t)m * 128 + j] = acc / fmaxf(cnt, 1.f);
}

// fp32 VALU GEMM for the tiny head (M=2000).
__global__ __launch_bounds__(256)
void k_gemm_f32(const float* __restrict__ X, const float* __restrict__ W,
                const float* __restrict__ bout, float* __restrict__ Y, int nrows) {
    __shared__ float Ws[64 * 128];
    __shared__ float Xs[32 * 128];
    const int tid = threadIdx.x;
    const int row0 = blockIdx.x * 32;

    {
        float4* Xsv = (float4*)Xs;
        #pragma unroll
        for (int i = 0; i < 4; ++i) {
            int idx = tid + 256 * i;
            int r = idx >> 5, c4 = idx & 31;
            int gr = row0 + r;
            float4 v = {0.f, 0.f, 0.f, 0.f};
            if (gr < nrows) v = *(const float4*)&X[(size_t)gr * 128 + c4 * 4];
            Xsv[idx] = v;
        }
    }

    const int tx = tid & 31;
    const int ty = tid >> 5;
    float4 acc[4];
    #pragma unroll
    for (int r = 0; r < 4; ++r) acc[r] = {0.f, 0.f, 0.f, 0.f};

    for (int kk = 0; kk < 128; kk += 64) {
        __syncthreads();
        const float4* Wv = (const float4*)(W + kk * 128);
        float4* Wsv = (float4*)Ws;
        #pragma unroll
        for (int i = 0; i < 8; ++i) Wsv[tid + 256 * i] = Wv[tid + 256 * i];
        __syncthreads();

        #pragma unroll 4
        for (int k = 0; k < 64; ++k) {
            float4 wv = *(const float4*)&Ws[k * 128 + tx * 4];
            #pragma unroll
            for (int r = 0; r < 4; ++r) {
                float xv = Xs[(ty + 8 * r) * 128 + kk + k];
                acc[r].x += xv * wv.x;
                acc[r].y += xv * wv.y;
                acc[r].z += xv * wv.z;
                acc[r].w += xv * wv.w;
            }
        }
    }

    #pragma unroll
    for (int r = 0; r < 4; ++r) {
        int gr = row0 + ty + 8 * r;
        if (gr < nrows) {
            float4 o = acc[r];
            float4 b = *(const float4*)&bout[tx * 4];
            o.x += b.x; o.y += b.y; o.z += b.z; o.w += b.w;
            *(float4*)&Y[(size_t)gr * 128 + tx * 4] = o;
        }
    }
}

extern "C" void kernel_launch(void* const* d_in, const int* in_sizes, int n_in,
                              void* d_out, int out_size, void* d_ws, size_t ws_size,
                              hipStream_t stream) {
    const float* x   = (const float*)d_in[0];
    const int*   ei  = (const int*)d_in[1];
    const int*   bat = (const int*)d_in[2];
    const float* W1  = (const float*)d_in[3];
    const float* b1  = (const float*)d_in[4];
    const float* W2  = (const float*)d_in[5];
    const float* b2  = (const float*)d_in[6];
    const float* Wf  = (const float*)d_in[7];
    const float* bf  = (const float*)d_in[8];
    float* out = (float*)d_out;

    const int N = in_sizes[0] / 128;
    const int E = in_sizes[1] / 2;
    const int M = out_size / 128;
    const int* src = ei;
    const int* dst = ei + E;

    char* ws = (char*)d_ws;
    const size_t featb = (size_t)N * 128 * 2;   // bf16 feature plane
    size_t off = 0;
    unsigned short* A   = (unsigned short*)(ws + off); off += (featb + 15) & ~15ull;
    unsigned short* B   = (unsigned short*)(ws + off); off += (featb + 15) & ~15ull;
    float* dis          = (float*)(ws + off); off += (((size_t)N * 4) + 15) & ~15ull;
    int*   counts       = (int*)  (ws + off); off += (((size_t)N * 4) + 15) & ~15ull;
    int*   rowStart     = (int*)  (ws + off); off += (((size_t)(N + 1) * 4) + 15) & ~15ull;
    int*   eidx         = (int*)  (ws + off); off += (((size_t)E * 4) + 15) & ~15ull;
    int*   chunkSum     = (int*)  (ws + off); off += 256 * 4;
    int*   chunkOff     = (int*)  (ws + off); off += 256 * 4;
    unsigned short* Wt1 = (unsigned short*)(ws + off); off += 128 * 128 * 2;
    unsigned short* Wt2 = (unsigned short*)(ws + off); off += 128 * 128 * 2;
    float* Z            = (float*)(ws + off); off += (size_t)M * 128 * 4;

    const int nChunks = (N + CHUNK - 1) / CHUNK;
    const int gemm_blocks = (N + 63) / 64;

    // 1. histogram + dis
    hipMemsetAsync(counts, 0, (size_t)N * sizeof(int), stream);
    k_hist<<<(E + 255) / 256, 256, 0, stream>>>(dst, counts, E);
    k_dis<<<(N + 255) / 256, 256, 0, stream>>>(counts, dis, N);

    // 2. CSR build
    k_blocksum<<<nChunks, 256, 0, stream>>>(counts, chunkSum, N);
    k_scanchunks<<<1, 256, 0, stream>>>(chunkSum, chunkOff, rowStart, nChunks, N, E);
    k_scanwrite<<<nChunks, 256, 0, stream>>>(counts, chunkOff, rowStart, counts, N);
    k_place<<<(E + 255) / 256, 256, 0, stream>>>(src, dst, counts, eidx, E);

    // 3. W transposes (bf16)
    k_prepw<<<64, 256, 0, stream>>>(W1, Wt1);
    k_prepw<<<64, 256, 0, stream>>>(W2, Wt2);

    // 4. A = x @ W1
    k_gemm_mfma<false, false><<<gemm_blocks, 256, 0, stream>>>(x, Wt1, nullptr, A, N);

    // 5. B = gather(A)
    k_gather<<<(N + 15) / 16, 256, 0, stream>>>(A, dis, rowStart, eidx, B, N);

    // 6. A = relu(B + b1) @ W2
    k_gemm_mfma<true, true><<<gemm_blocks, 256, 0, stream>>>(B, Wt2, b1, A, N);

    // 7. B = gather(A)
    k_gather<<<(N + 15) / 16, 256, 0, stream>>>(A, dis, rowStart, eidx, B, N);

    // 8. Z = segment-mean(relu(B + b2))
    k_pool<<<M, 128, 0, stream>>>(B, b2, bat, Z, N);

    // 9. out = Z @ Wf + bf
    k_gemm_f32<<<(M + 31) / 32, 256, 0, stream>>>(Z, Wf, bf, out, M);
}

// Round 14
// 372.655 us; speedup vs baseline: 1.5723x; 1.0337x over previous
//
#include <hip/hip_runtime.h>
#include <hip/hip_bf16.h>

// Pipeline (bf16 storage, fp32 accumulate):
//  1. counts = in-degree hist; dis = rsqrt(deg+1)
//  2. CSR by dst (blocksum/scan/scanwrite/place)
//  3. Wt1/Wt2 = transpose(W1/W2) cast bf16  [col][k]
//  4. A(bf16) = x @ W1                       (persistent MFMA, reg-prefetch pipeline)
//  5. B(bf16) = relu(gather(A) + b1)         (bias+relu fused into gather epilogue)
//  6. A(bf16) = B @ W2                       (pure bf16 staging)
//  7. B(bf16) = relu(gather(A) + b2)
//  8. Z(f32)  = segment-mean(B)              (pure mean)
//  9. out = Z @ Wf + bf                      (fp32 VALU, tiny)

typedef __attribute__((ext_vector_type(8))) short short8;
typedef __attribute__((ext_vector_type(8))) unsigned short ushort8v;
typedef __attribute__((ext_vector_type(4))) unsigned short ushort4v;
typedef __attribute__((ext_vector_type(4))) float f32x4;

#define XPADB 136     // LDS row stride in bf16 elems (128+8); 272B: 16B-aligned, ~2-way banks
#define CHUNK 1024
#define GEMM_GRID 768 // 3 blocks/CU x 256 CU (LDS-bound occupancy)

static __device__ __forceinline__ unsigned short f2b(float f) {   // RNE f32->bf16
    unsigned u = __builtin_bit_cast(unsigned, f);
    return (unsigned short)((u + 0x7FFFu + ((u >> 16) & 1u)) >> 16);
}
static __device__ __forceinline__ float b2f(unsigned short h) {
    unsigned u = ((unsigned)h) << 16;
    return __builtin_bit_cast(float, u);
}

__global__ __launch_bounds__(256)
void k_hist(const int* __restrict__ dst, int* __restrict__ counts, int E) {
    int i = blockIdx.x * 256 + threadIdx.x;
    if (i < E) atomicAdd(&counts[dst[i]], 1);
}

__global__ __launch_bounds__(256)
void k_dis(const int* __restrict__ counts, float* __restrict__ dis, int N) {
    int i = blockIdx.x * 256 + threadIdx.x;
    if (i < N) dis[i] = rsqrtf((float)counts[i] + 1.0f);
}

__global__ __launch_bounds__(256)
void k_blocksum(const int* __restrict__ counts, int* __restrict__ chunkSum, int N) {
    __shared__ int s[256];
    int b = blockIdx.x, t = threadIdx.x;
    int base = b * CHUNK + t * 4;
    int p = 0;
    #pragma unroll
    for (int i = 0; i < 4; ++i) if (base + i < N) p += counts[base + i];
    s[t] = p; __syncthreads();
    for (int off = 128; off > 0; off >>= 1) {
        if (t < off) s[t] += s[t + off];
        __syncthreads();
    }
    if (t == 0) chunkSum[b] = s[0];
}

__global__ __launch_bounds__(256)
void k_scanchunks(const int* __restrict__ chunkSum, int* __restrict__ chunkOff,
                  int* __restrict__ rowStart, int nChunks, int N, int E) {
    __shared__ int s[256];
    int t = threadIdx.x;
    int v = (t < nChunks) ? chunkSum[t] : 0;
    s[t] = v; __syncthreads();
    for (int off = 1; off < 256; off <<= 1) {
        int u = (t >= off) ? s[t - off] : 0;
        __syncthreads();
        s[t] += u;
        __syncthreads();
    }
    if (t < nChunks) chunkOff[t] = s[t] - v;
    if (t == 0) rowStart[N] = E;
}

// counts/cursor may alias (read-before-write per thread) -> no __restrict__
__global__ __launch_bounds__(256)
void k_scanwrite(const int* counts, const int* __restrict__ chunkOff,
                 int* __restrict__ rowStart, int* cursor, int N) {
    __shared__ int s[256];
    int b = blockIdx.x, t = threadIdx.x;
    int base = b * CHUNK + t * 4;
    int c[4]; int p = 0;
    #pragma unroll
    for (int i = 0; i < 4; ++i) { c[i] = (base + i < N) ? counts[base + i] : 0; p += c[i]; }
    s[t] = p; __syncthreads();
    for (int off = 1; off < 256; off <<= 1) {
        int u = (t >= off) ? s[t - off] : 0;
        __syncthreads();
        s[t] += u;
        __syncthreads();
    }
    int off = chunkOff[b] + s[t] - p;
    #pragma unroll
    for (int i = 0; i < 4; ++i) {
        if (base + i < N) { rowStart[base + i] = off; cursor[base + i] = off; off += c[i]; }
    }
}

__global__ __launch_bounds__(256)
void k_place(const int* __restrict__ src, const int* __restrict__ dst,
             int* __restrict__ cursor, int* __restrict__ eidx, int E) {
    int e = blockIdx.x * 256 + threadIdx.x;
    if (e >= E) return;
    int d = dst[e];
    int pos = atomicAdd(&cursor[d], 1);
    eidx[pos] = src[e];
}

// Wt[c*128 + k] = bf16(W[k*128 + c])
__global__ __launch_bounds__(256)
void k_prepw(const float* __restrict__ W, unsigned short* __restrict__ Wt) {
    int i = blockIdx.x * 256 + threadIdx.x;
    if (i < 128 * 128) {
        int k = i >> 7, c = i & 127;
        Wt[c * 128 + k] = f2b(W[i]);
    }
}

// Persistent MFMA GEMM: Y(bf16) = X @ W over grid-strided 64-row tiles.
// W staged to LDS once per block; X tile register-prefetched (issue loads for
// tile t+1 -> compute tile t -> barrier -> ds_write -> barrier).
// 4 waves; wave w -> rows w*16..+15, 8 col-tiles. A/B frag slot->k maps match.
template<bool BF16_IN>
__global__ __launch_bounds__(256)
void k_gemm_mfma(const void* __restrict__ Xv, const unsigned short* __restrict__ Wt,
                 unsigned short* __restrict__ Y, int nrows, int nTiles) {
    __shared__ unsigned short Xs[64 * XPADB];    // [row][k]
    __shared__ unsigned short Ws[128 * XPADB];   // [col][k]
    const int tid = threadIdx.x;

    // stage Wt -> Ws once (L2-hot, 32KB)
    #pragma unroll
    for (int i = 0; i < 8; ++i) {
        int q = tid + 256 * i;
        int col = q >> 4, k8 = q & 15;
        *(short8*)&Ws[col * XPADB + k8 * 8] = *(const short8*)&Wt[col * 128 + k8 * 8];
    }

    const int l = tid & 63;
    const int w = tid >> 6;
    const int r = l & 15;
    const int g = l >> 4;

    // prefetch registers
    short8 xb[4];    // bf16 path: 4 x (8 shorts)
    float4 xf[8];    // fp32 path: 8 x (4 floats)

    int t = blockIdx.x;

    // ---- prologue: load tile t into regs ----
    if (BF16_IN) {
        const unsigned short* X = (const unsigned short*)Xv;
        #pragma unroll
        for (int i = 0; i < 4; ++i) {
            int q = tid + 256 * i;              // 64 rows x 16 chunks
            int row = q >> 4, k8 = q & 15;
            int gr = t * 64 + row;
            xb[i] = (gr < nrows) ? *(const short8*)&X[(size_t)gr * 128 + k8 * 8]
                                 : (short8){0,0,0,0,0,0,0,0};
        }
    } else {
        const float* X = (const float*)Xv;
        #pragma unroll
        for (int i = 0; i < 8; ++i) {
            int q = tid + 256 * i;              // 64 rows x 32 float4-chunks
            int row = q >> 5, c4 = q & 31;
            int gr = t * 64 + row;
            xf[i] = (gr < nrows) ? *(const float4*)&X[(size_t)gr * 128 + c4 * 4]
                                 : (float4){0.f, 0.f, 0.f, 0.f};
        }
    }
    // write tile t to LDS
    if (BF16_IN) {
        #pragma unroll
        for (int i = 0; i < 4; ++i) {
            int q = tid + 256 * i;
            int row = q >> 4, k8 = q & 15;
            *(short8*)&Xs[row * XPADB + k8 * 8] = xb[i];
        }
    } else {
        #pragma unroll
        for (int i = 0; i < 8; ++i) {
            int q = tid + 256 * i;
            int row = q >> 5, c4 = q & 31;
            *(ushort4v*)&Xs[row * XPADB + c4 * 4] =
                (ushort4v){f2b(xf[i].x), f2b(xf[i].y), f2b(xf[i].z), f2b(xf[i].w)};
        }
    }
    __syncthreads();   // Ws + Xs ready

    for (;;) {
        int next = t + gridDim.x;
        bool more = next < nTiles;

        // ---- issue loads for tile next (no wait; hidden under compute) ----
        if (more) {
            if (BF16_IN) {
                const unsigned short* X = (const unsigned short*)Xv;
                #pragma unroll
                for (int i = 0; i < 4; ++i) {
                    int q = tid + 256 * i;
                    int row = q >> 4, k8 = q & 15;
                    int gr = next * 64 + row;
                    xb[i] = (gr < nrows) ? *(const short8*)&X[(size_t)gr * 128 + k8 * 8]
                                         : (short8){0,0,0,0,0,0,0,0};
                }
            } else {
                const float* X = (const float*)Xv;
                #pragma unroll
                for (int i = 0; i < 8; ++i) {
                    int q = tid + 256 * i;
                    int row = q >> 5, c4 = q & 31;
                    int gr = next * 64 + row;
                    xf[i] = (gr < nrows) ? *(const float4*)&X[(size_t)gr * 128 + c4 * 4]
                                         : (float4){0.f, 0.f, 0.f, 0.f};
                }
            }
        }

        // ---- compute tile t from LDS ----
        f32x4 acc[8];
        #pragma unroll
        for (int n = 0; n < 8; ++n) acc[n] = (f32x4){0.f, 0.f, 0.f, 0.f};

        #pragma unroll
        for (int kk = 0; kk < 4; ++kk) {
            short8 af = *(const short8*)&Xs[(w * 16 + r) * XPADB + kk * 32 + g * 8];
            #pragma unroll
            for (int n = 0; n < 8; ++n) {
                short8 bfr = *(const short8*)&Ws[(n * 16 + r) * XPADB + kk * 32 + g * 8];
                acc[n] = __builtin_amdgcn_mfma_f32_16x16x32_bf16(af, bfr, acc[n], 0, 0, 0);
            }
        }

        // C/D: col = lane&15, row = (lane>>4)*4 + j   [HW-verified m89]
        const int row0 = t * 64;
        #pragma unroll
        for (int n = 0; n < 8; ++n) {
            #pragma unroll
            for (int j = 0; j < 4; ++j) {
                int grow = row0 + w * 16 + g * 4 + j;
                if (grow < nrows)
                    Y[(size_t)grow * 128 + n * 16 + r] = f2b(acc[n][j]);
            }
        }

        if (!more) break;

        __syncthreads();   // all waves done reading Xs for tile t
        if (BF16_IN) {
            #pragma unroll
            for (int i = 0; i < 4; ++i) {
                int q = tid + 256 * i;
                int row = q >> 4, k8 = q & 15;
                *(short8*)&Xs[row * XPADB + k8 * 8] = xb[i];
            }
        } else {
            #pragma unroll
            for (int i = 0; i < 8; ++i) {
                int q = tid + 256 * i;
                int row = q >> 5, c4 = q & 31;
                *(ushort4v*)&Xs[row * XPADB + c4 * 4] =
                    (ushort4v){f2b(xf[i].x), f2b(xf[i].y), f2b(xf[i].z), f2b(xf[i].w)};
            }
        }
        __syncthreads();
        t = next;
    }
}

// gather + fused bias+relu epilogue: B[d,:] = relu(Ahat_row + bias).
// 16 lanes/node (lane = 8 bf16 cols), 4 nodes/wave, edge loop unrolled x2.
__global__ __launch_bounds__(256)
void k_gather(const unsigned short* __restrict__ A, const float* __restrict__ dis,
              const int* __restrict__ rowStart, const int* __restrict__ eidx,
              const float* __restrict__ bias, unsigned short* __restrict__ B, int N) {
    int d = blockIdx.x * 16 + (threadIdx.x >> 4);
    if (d >= N) return;
    int lane = threadIdx.x & 15;
    float dd = dis[d];
    int beg = rowStart[d], end = rowStart[d + 1];

    float acc[8];
    {
        ushort8v v = *(const ushort8v*)&A[(size_t)d * 128 + lane * 8];
        float s = dd * dd;                       // self loop
        #pragma unroll
        for (int e = 0; e < 8; ++e) acc[e] = s * b2f((unsigned short)v[e]);
    }
    int j = beg;
    for (; j + 2 <= end; j += 2) {
        int s0 = eidx[j], s1 = eidx[j + 1];
        float n0 = dd * dis[s0], n1 = dd * dis[s1];
        ushort8v u0 = *(const ushort8v*)&A[(size_t)s0 * 128 + lane * 8];
        ushort8v u1 = *(const ushort8v*)&A[(size_t)s1 * 128 + lane * 8];
        #pragma unroll
        for (int e = 0; e < 8; ++e)
            acc[e] += n0 * b2f((unsigned short)u0[e]) + n1 * b2f((unsigned short)u1[e]);
    }
    if (j < end) {
        int s0 = eidx[j];
        float n0 = dd * dis[s0];
        ushort8v u0 = *(const ushort8v*)&A[(size_t)s0 * 128 + lane * 8];
        #pragma unroll
        for (int e = 0; e < 8; ++e) acc[e] += n0 * b2f((unsigned short)u0[e]);
    }
    float4 bv0 = *(const float4*)&bias[lane * 8];
    float4 bv1 = *(const float4*)&bias[lane * 8 + 4];
    ushort8v o;
    o[0] = f2b(fmaxf(acc[0] + bv0.x, 0.f));
    o[1] = f2b(fmaxf(acc[1] + bv0.y, 0.f));
    o[2] = f2b(fmaxf(acc[2] + bv0.z, 0.f));
    o[3] = f2b(fmaxf(acc[3] + bv0.w, 0.f));
    o[4] = f2b(fmaxf(acc[4] + bv1.x, 0.f));
    o[5] = f2b(fmaxf(acc[5] + bv1.y, 0.f));
    o[6] = f2b(fmaxf(acc[6] + bv1.z, 0.f));
    o[7] = f2b(fmaxf(acc[7] + bv1.w, 0.f));
    *(ushort8v*)&B[(size_t)d * 128 + lane * 8] = o;
}

// segment mean (H already activated); batch sorted. one block per segment.
__global__ __launch_bounds__(128)
void k_pool(const unsigned short* __restrict__ H,
            const int* __restrict__ batch, float* __restrict__ Z, int N) {
    int m = blockIdx.x;
    int lo = 0, hi = N;
    while (lo < hi) { int mid = (lo + hi) >> 1; if (batch[mid] < m) lo = mid + 1; else hi = mid; }
    int start = lo;
    hi = N;
    while (lo < hi) { int mid = (lo + hi) >> 1; if (batch[mid] < m + 1) lo = mid + 1; else hi = mid; }
    int end = lo;

    int j = threadIdx.x;
    float acc = 0.f;
    for (int i = start; i < end; ++i)
        acc += b2f(H[(size_t)i * 128 + j]);
    float cnt = (float)(end - start);
    Z[(size_t)m * 128 + j] = acc / fmaxf(cnt, 1.f);
}

// fp32 VALU GEMM for the tiny head (M=2000).
__global__ __launch_bounds__(256)
void k_gemm_f32(const float* __restrict__ X, const float* __restrict__ W,
                const float* __restrict__ bout, float* __restrict__ Y, int nrows) {
    __shared__ float Ws[64 * 128];
    __shared__ float Xs[32 * 128];
    const int tid = threadIdx.x;
    const int row0 = blockIdx.x * 32;

    {
        float4* Xsv = (float4*)Xs;
        #pragma unroll
        for (int i = 0; i < 4; ++i) {
            int idx = tid + 256 * i;
            int r = idx >> 5, c4 = idx & 31;
            int gr = row0 + r;
            float4 v = {0.f, 0.f, 0.f, 0.f};
            if (gr < nrows) v = *(const float4*)&X[(size_t)gr * 128 + c4 * 4];
            Xsv[idx] = v;
        }
    }

    const int tx = tid & 31;
    const int ty = tid >> 5;
    float4 acc[4];
    #pragma unroll
    for (int r = 0; r < 4; ++r) acc[r] = {0.f, 0.f, 0.f, 0.f};

    for (int kk = 0; kk < 128; kk += 64) {
        __syncthreads();
        const float4* Wv = (const float4*)(W + kk * 128);
        float4* Wsv = (float4*)Ws;
        #pragma unroll
        for (int i = 0; i < 8; ++i) Wsv[tid + 256 * i] = Wv[tid + 256 * i];
        __syncthreads();

        #pragma unroll 4
        for (int k = 0; k < 64; ++k) {
            float4 wv = *(const float4*)&Ws[k * 128 + tx * 4];
            #pragma unroll
            for (int r = 0; r < 4; ++r) {
                float xv = Xs[(ty + 8 * r) * 128 + kk + k];
                acc[r].x += xv * wv.x;
                acc[r].y += xv * wv.y;
                acc[r].z += xv * wv.z;
                acc[r].w += xv * wv.w;
            }
        }
    }

    #pragma unroll
    for (int r = 0; r < 4; ++r) {
        int gr = row0 + ty + 8 * r;
        if (gr < nrows) {
            float4 o = acc[r];
            float4 b = *(const float4*)&bout[tx * 4];
            o.x += b.x; o.y += b.y; o.z += b.z; o.w += b.w;
            *(float4*)&Y[(size_t)gr * 128 + tx * 4] = o;
        }
    }
}

extern "C" void kernel_launch(void* const* d_in, const int* in_sizes, int n_in,
                              void* d_out, int out_size, void* d_ws, size_t ws_size,
                              hipStream_t stream) {
    const float* x   = (const float*)d_in[0];
    const int*   ei  = (const int*)d_in[1];
    const int*   bat = (const int*)d_in[2];
    const float* W1  = (const float*)d_in[3];
    const float* b1  = (const float*)d_in[4];
    const float* W2  = (const float*)d_in[5];
    const float* b2  = (const float*)d_in[6];
    const float* Wf  = (const float*)d_in[7];
    const float* bf  = (const float*)d_in[8];
    float* out = (float*)d_out;

    const int N = in_sizes[0] / 128;
    const int E = in_sizes[1] / 2;
    const int M = out_size / 128;
    const int* src = ei;
    const int* dst = ei + E;

    char* ws = (char*)d_ws;
    const size_t featb = (size_t)N * 128 * 2;   // bf16 feature plane
    size_t off = 0;
    unsigned short* A   = (unsigned short*)(ws + off); off += (featb + 15) & ~15ull;
    unsigned short* B   = (unsigned short*)(ws + off); off += (featb + 15) & ~15ull;
    float* dis          = (float*)(ws + off); off += (((size_t)N * 4) + 15) & ~15ull;
    int*   counts       = (int*)  (ws + off); off += (((size_t)N * 4) + 15) & ~15ull;
    int*   rowStart     = (int*)  (ws + off); off += (((size_t)(N + 1) * 4) + 15) & ~15ull;
    int*   eidx         = (int*)  (ws + off); off += (((size_t)E * 4) + 15) & ~15ull;
    int*   chunkSum     = (int*)  (ws + off); off += 256 * 4;
    int*   chunkOff     = (int*)  (ws + off); off += 256 * 4;
    unsigned short* Wt1 = (unsigned short*)(ws + off); off += 128 * 128 * 2;
    unsigned short* Wt2 = (unsigned short*)(ws + off); off += 128 * 128 * 2;
    float* Z            = (float*)(ws + off); off += (size_t)M * 128 * 4;

    const int nChunks = (N + CHUNK - 1) / CHUNK;
    const int nTiles = (N + 63) / 64;
    const int gemm_grid = nTiles < GEMM_GRID ? nTiles : GEMM_GRID;

    // 1. histogram + dis
    hipMemsetAsync(counts, 0, (size_t)N * sizeof(int), stream);
    k_hist<<<(E + 255) / 256, 256, 0, stream>>>(dst, counts, E);
    k_dis<<<(N + 255) / 256, 256, 0, stream>>>(counts, dis, N);

    // 2. CSR build
    k_blocksum<<<nChunks, 256, 0, stream>>>(counts, chunkSum, N);
    k_scanchunks<<<1, 256, 0, stream>>>(chunkSum, chunkOff, rowStart, nChunks, N, E);
    k_scanwrite<<<nChunks, 256, 0, stream>>>(counts, chunkOff, rowStart, counts, N);
    k_place<<<(E + 255) / 256, 256, 0, stream>>>(src, dst, counts, eidx, E);

    // 3. W transposes (bf16)
    k_prepw<<<64, 256, 0, stream>>>(W1, Wt1);
    k_prepw<<<64, 256, 0, stream>>>(W2, Wt2);

    // 4. A = x @ W1
    k_gemm_mfma<false><<<gemm_grid, 256, 0, stream>>>(x, Wt1, A, N, nTiles);

    // 5. B = relu(gather(A) + b1)
    k_gather<<<(N + 15) / 16, 256, 0, stream>>>(A, dis, rowStart, eidx, b1, B, N);

    // 6. A = B @ W2
    k_gemm_mfma<true><<<gemm_grid, 256, 0, stream>>>(B, Wt2, A, N, nTiles);

    // 7. B = relu(gather(A) + b2)
    k_gather<<<(N + 15) / 16, 256, 0, stream>>>(A, dis, rowStart, eidx, b2, B, N);

    // 8. Z = segment-mean(B)
    k_pool<<<M, 128, 0, stream>>>(B, bat, Z, N);

    // 9. out = Z @ Wf + bf
    k_gemm_f32<<<(M + 31) / 32, 256, 0, stream>>>(Z, Wf, bf, out, M);
}

// Round 15
// 358.022 us; speedup vs baseline: 1.6365x; 1.0409x over previous
//
#include <hip/hip_runtime.h>
#include <hip/hip_bf16.h>

// Pipeline (bf16 storage, fp32 accumulate):
//  1. counts = in-degree hist
//  2. CSR by dst (blocksum/scanchunks/scanwrite[+dis]/place)
//  3. Wt1/Wt2 = transpose(W1/W2) cast bf16 (one kernel)
//  4. A(bf16) = x @ W1                       (persistent MFMA, reg-prefetch)
//  5. B(bf16) = relu(gather(A) + b1)         (XCD-swizzled blocks)
//  6. A(bf16) = B @ W2
//  7. B(bf16) = relu(gather(A) + b2)
//  8. out = segmean(B) @ Wf + bf             (fused pool+head)

typedef __attribute__((ext_vector_type(8))) short short8;
typedef __attribute__((ext_vector_type(8))) unsigned short ushort8v;
typedef __attribute__((ext_vector_type(4))) unsigned short ushort4v;
typedef __attribute__((ext_vector_type(4))) float f32x4;

#define XPADB 136     // LDS row stride in bf16 elems (128+8); 272B: 16B-aligned, ~2-way banks
#define CHUNK 1024
#define GEMM_GRID 768 // 3 blocks/CU x 256 CU (LDS-bound occupancy)

static __device__ __forceinline__ unsigned short f2b(float f) {   // RNE f32->bf16
    unsigned u = __builtin_bit_cast(unsigned, f);
    return (unsigned short)((u + 0x7FFFu + ((u >> 16) & 1u)) >> 16);
}
static __device__ __forceinline__ float b2f(unsigned short h) {
    unsigned u = ((unsigned)h) << 16;
    return __builtin_bit_cast(float, u);
}

__global__ __launch_bounds__(256)
void k_hist(const int* __restrict__ dst, int* __restrict__ counts, int E) {
    int i = blockIdx.x * 256 + threadIdx.x;
    if (i < E) atomicAdd(&counts[dst[i]], 1);
}

__global__ __launch_bounds__(256)
void k_blocksum(const int* __restrict__ counts, int* __restrict__ chunkSum, int N) {
    __shared__ int s[256];
    int b = blockIdx.x, t = threadIdx.x;
    int base = b * CHUNK + t * 4;
    int p = 0;
    #pragma unroll
    for (int i = 0; i < 4; ++i) if (base + i < N) p += counts[base + i];
    s[t] = p; __syncthreads();
    for (int off = 128; off > 0; off >>= 1) {
        if (t < off) s[t] += s[t + off];
        __syncthreads();
    }
    if (t == 0) chunkSum[b] = s[0];
}

__global__ __launch_bounds__(256)
void k_scanchunks(const int* __restrict__ chunkSum, int* __restrict__ chunkOff,
                  int* __restrict__ rowStart, int nChunks, int N, int E) {
    __shared__ int s[256];
    int t = threadIdx.x;
    int v = (t < nChunks) ? chunkSum[t] : 0;
    s[t] = v; __syncthreads();
    for (int off = 1; off < 256; off <<= 1) {
        int u = (t >= off) ? s[t - off] : 0;
        __syncthreads();
        s[t] += u;
        __syncthreads();
    }
    if (t < nChunks) chunkOff[t] = s[t] - v;
    if (t == 0) rowStart[N] = E;
}

// counts/cursor may alias (read-before-write per thread) -> no __restrict__ on those.
// Also emits dis[i] = rsqrt(counts[i]+1) (fused former k_dis).
__global__ __launch_bounds__(256)
void k_scanwrite(const int* counts, const int* __restrict__ chunkOff,
                 int* __restrict__ rowStart, int* cursor,
                 float* __restrict__ disv, int N) {
    __shared__ int s[256];
    int b = blockIdx.x, t = threadIdx.x;
    int base = b * CHUNK + t * 4;
    int c[4]; int p = 0;
    #pragma unroll
    for (int i = 0; i < 4; ++i) { c[i] = (base + i < N) ? counts[base + i] : 0; p += c[i]; }
    s[t] = p; __syncthreads();
    for (int off = 1; off < 256; off <<= 1) {
        int u = (t >= off) ? s[t - off] : 0;
        __syncthreads();
        s[t] += u;
        __syncthreads();
    }
    int off = chunkOff[b] + s[t] - p;
    #pragma unroll
    for (int i = 0; i < 4; ++i) {
        if (base + i < N) {
            rowStart[base + i] = off;
            cursor[base + i] = off;
            disv[base + i] = rsqrtf((float)c[i] + 1.0f);
            off += c[i];
        }
    }
}

__global__ __launch_bounds__(256)
void k_place(const int* __restrict__ src, const int* __restrict__ dst,
             int* __restrict__ cursor, int* __restrict__ eidx, int E) {
    int e = blockIdx.x * 256 + threadIdx.x;
    if (e >= E) return;
    int d = dst[e];
    int pos = atomicAdd(&cursor[d], 1);
    eidx[pos] = src[e];
}

// Both weight transposes in one launch: grid 128 x 256 covers 2*16384 elems.
__global__ __launch_bounds__(256)
void k_prepw2(const float* __restrict__ W1, const float* __restrict__ W2,
              unsigned short* __restrict__ Wt1, unsigned short* __restrict__ Wt2) {
    int i = blockIdx.x * 256 + threadIdx.x;
    const float* W = (i < 16384) ? W1 : W2;
    unsigned short* Wt = (i < 16384) ? Wt1 : Wt2;
    int ii = i & 16383;
    int k = ii >> 7, c = ii & 127;
    Wt[c * 128 + k] = f2b(W[ii]);
}

// Persistent MFMA GEMM: Y(bf16) = X @ W over grid-strided 64-row tiles.
// W staged to LDS once per block; X tile register-prefetched.
template<bool BF16_IN>
__global__ __launch_bounds__(256)
void k_gemm_mfma(const void* __restrict__ Xv, const unsigned short* __restrict__ Wt,
                 unsigned short* __restrict__ Y, int nrows, int nTiles) {
    __shared__ unsigned short Xs[64 * XPADB];    // [row][k]
    __shared__ unsigned short Ws[128 * XPADB];   // [col][k]
    const int tid = threadIdx.x;

    #pragma unroll
    for (int i = 0; i < 8; ++i) {
        int q = tid + 256 * i;
        int col = q >> 4, k8 = q & 15;
        *(short8*)&Ws[col * XPADB + k8 * 8] = *(const short8*)&Wt[col * 128 + k8 * 8];
    }

    const int l = tid & 63;
    const int w = tid >> 6;
    const int r = l & 15;
    const int g = l >> 4;

    short8 xb[4];
    float4 xf[8];

    int t = blockIdx.x;

    if (BF16_IN) {
        const unsigned short* X = (const unsigned short*)Xv;
        #pragma unroll
        for (int i = 0; i < 4; ++i) {
            int q = tid + 256 * i;
            int row = q >> 4, k8 = q & 15;
            int gr = t * 64 + row;
            xb[i] = (gr < nrows) ? *(const short8*)&X[(size_t)gr * 128 + k8 * 8]
                                 : (short8){0,0,0,0,0,0,0,0};
        }
    } else {
        const float* X = (const float*)Xv;
        #pragma unroll
        for (int i = 0; i < 8; ++i) {
            int q = tid + 256 * i;
            int row = q >> 5, c4 = q & 31;
            int gr = t * 64 + row;
            xf[i] = (gr < nrows) ? *(const float4*)&X[(size_t)gr * 128 + c4 * 4]
                                 : (float4){0.f, 0.f, 0.f, 0.f};
        }
    }
    if (BF16_IN) {
        #pragma unroll
        for (int i = 0; i < 4; ++i) {
            int q = tid + 256 * i;
            int row = q >> 4, k8 = q & 15;
            *(short8*)&Xs[row * XPADB + k8 * 8] = xb[i];
        }
    } else {
        #pragma unroll
        for (int i = 0; i < 8; ++i) {
            int q = tid + 256 * i;
            int row = q >> 5, c4 = q & 31;
            *(ushort4v*)&Xs[row * XPADB + c4 * 4] =
                (ushort4v){f2b(xf[i].x), f2b(xf[i].y), f2b(xf[i].z), f2b(xf[i].w)};
        }
    }
    __syncthreads();

    for (;;) {
        int next = t + gridDim.x;
        bool more = next < nTiles;

        if (more) {
            if (BF16_IN) {
                const unsigned short* X = (const unsigned short*)Xv;
                #pragma unroll
                for (int i = 0; i < 4; ++i) {
                    int q = tid + 256 * i;
                    int row = q >> 4, k8 = q & 15;
                    int gr = next * 64 + row;
                    xb[i] = (gr < nrows) ? *(const short8*)&X[(size_t)gr * 128 + k8 * 8]
                                         : (short8){0,0,0,0,0,0,0,0};
                }
            } else {
                const float* X = (const float*)Xv;
                #pragma unroll
                for (int i = 0; i < 8; ++i) {
                    int q = tid + 256 * i;
                    int row = q >> 5, c4 = q & 31;
                    int gr = next * 64 + row;
                    xf[i] = (gr < nrows) ? *(const float4*)&X[(size_t)gr * 128 + c4 * 4]
                                         : (float4){0.f, 0.f, 0.f, 0.f};
                }
            }
        }

        f32x4 acc[8];
        #pragma unroll
        for (int n = 0; n < 8; ++n) acc[n] = (f32x4){0.f, 0.f, 0.f, 0.f};

        #pragma unroll
        for (int kk = 0; kk < 4; ++kk) {
            short8 af = *(const short8*)&Xs[(w * 16 + r) * XPADB + kk * 32 + g * 8];
            #pragma unroll
            for (int n = 0; n < 8; ++n) {
                short8 bfr = *(const short8*)&Ws[(n * 16 + r) * XPADB + kk * 32 + g * 8];
                acc[n] = __builtin_amdgcn_mfma_f32_16x16x32_bf16(af, bfr, acc[n], 0, 0, 0);
            }
        }

        const int row0 = t * 64;
        #pragma unroll
        for (int n = 0; n < 8; ++n) {
            #pragma unroll
            for (int j = 0; j < 4; ++j) {
                int grow = row0 + w * 16 + g * 4 + j;
                if (grow < nrows)
                    Y[(size_t)grow * 128 + n * 16 + r] = f2b(acc[n][j]);
            }
        }

        if (!more) break;

        __syncthreads();
        if (BF16_IN) {
            #pragma unroll
            for (int i = 0; i < 4; ++i) {
                int q = tid + 256 * i;
                int row = q >> 4, k8 = q & 15;
                *(short8*)&Xs[row * XPADB + k8 * 8] = xb[i];
            }
        } else {
            #pragma unroll
            for (int i = 0; i < 8; ++i) {
                int q = tid + 256 * i;
                int row = q >> 5, c4 = q & 31;
                *(ushort4v*)&Xs[row * XPADB + c4 * 4] =
                    (ushort4v){f2b(xf[i].x), f2b(xf[i].y), f2b(xf[i].z), f2b(xf[i].w)};
            }
        }
        __syncthreads();
        t = next;
    }
}

// gather + fused bias+relu. 16 lanes/node, 4 nodes/wave, x2 unroll.
// XCD-aware bijective block swizzle: contiguous node-chunks -> same XCD L2
// (batch-sorted nodes => tree-edge srcs are near dst => per-XCD L2 reuse).
__global__ __launch_bounds__(256)
void k_gather(const unsigned short* __restrict__ A, const float* __restrict__ dis,
              const int* __restrict__ rowStart, const int* __restrict__ eidx,
              const float* __restrict__ bias, unsigned short* __restrict__ B,
              int N, int nBlocks) {
    int bid = blockIdx.x;
    int q = nBlocks >> 3, rr = nBlocks & 7;
    int xcd = bid & 7, idx = bid >> 3;
    int swz = (xcd < rr ? xcd * (q + 1) : rr * (q + 1) + (xcd - rr) * q) + idx;

    int d = swz * 16 + (threadIdx.x >> 4);
    if (d >= N) return;
    int lane = threadIdx.x & 15;
    float dd = dis[d];
    int beg = rowStart[d], end = rowStart[d + 1];

    float acc[8];
    {
        ushort8v v = *(const ushort8v*)&A[(size_t)d * 128 + lane * 8];
        float s = dd * dd;                       // self loop
        #pragma unroll
        for (int e = 0; e < 8; ++e) acc[e] = s * b2f((unsigned short)v[e]);
    }
    int j = beg;
    for (; j + 2 <= end; j += 2) {
        int s0 = eidx[j], s1 = eidx[j + 1];
        float n0 = dd * dis[s0], n1 = dd * dis[s1];
        ushort8v u0 = *(const ushort8v*)&A[(size_t)s0 * 128 + lane * 8];
        ushort8v u1 = *(const ushort8v*)&A[(size_t)s1 * 128 + lane * 8];
        #pragma unroll
        for (int e = 0; e < 8; ++e)
            acc[e] += n0 * b2f((unsigned short)u0[e]) + n1 * b2f((unsigned short)u1[e]);
    }
    if (j < end) {
        int s0 = eidx[j];
        float n0 = dd * dis[s0];
        ushort8v u0 = *(const ushort8v*)&A[(size_t)s0 * 128 + lane * 8];
        #pragma unroll
        for (int e = 0; e < 8; ++e) acc[e] += n0 * b2f((unsigned short)u0[e]);
    }
    float4 bv0 = *(const float4*)&bias[lane * 8];
    float4 bv1 = *(const float4*)&bias[lane * 8 + 4];
    ushort8v o;
    o[0] = f2b(fmaxf(acc[0] + bv0.x, 0.f));
    o[1] = f2b(fmaxf(acc[1] + bv0.y, 0.f));
    o[2] = f2b(fmaxf(acc[2] + bv0.z, 0.f));
    o[3] = f2b(fmaxf(acc[3] + bv0.w, 0.f));
    o[4] = f2b(fmaxf(acc[4] + bv1.x, 0.f));
    o[5] = f2b(fmaxf(acc[5] + bv1.y, 0.f));
    o[6] = f2b(fmaxf(acc[6] + bv1.z, 0.f));
    o[7] = f2b(fmaxf(acc[7] + bv1.w, 0.f));
    *(ushort8v*)&B[(size_t)d * 128 + lane * 8] = o;
}

// fused pool + head: out[m,:] = segmean(H[seg m]) @ Wf + bf.
// one block of 128 per segment; z in LDS; Wf row-reads coalesced, L2-hot.
__global__ __launch_bounds__(128)
void k_poolhead(const unsigned short* __restrict__ H, const int* __restrict__ batch,
                const float* __restrict__ Wf, const float* __restrict__ bfv,
                float* __restrict__ out, int N) {
    __shared__ float z[128];
    int m = blockIdx.x;
    int lo = 0, hi = N;
    while (lo < hi) { int mid = (lo + hi) >> 1; if (batch[mid] < m) lo = mid + 1; else hi = mid; }
    int start = lo;
    hi = N;
    while (lo < hi) { int mid = (lo + hi) >> 1; if (batch[mid] < m + 1) lo = mid + 1; else hi = mid; }
    int end = lo;

    int j = threadIdx.x;
    float acc = 0.f;
    for (int i = start; i < end; ++i)
        acc += b2f(H[(size_t)i * 128 + j]);
    float cnt = (float)(end - start);
    z[j] = acc / fmaxf(cnt, 1.f);
    __syncthreads();

    float o = bfv[j];
    #pragma unroll 8
    for (int k = 0; k < 128; ++k)
        o += z[k] * Wf[k * 128 + j];
    out[(size_t)m * 128 + j] = o;
}

extern "C" void kernel_launch(void* const* d_in, const int* in_sizes, int n_in,
                              void* d_out, int out_size, void* d_ws, size_t ws_size,
                              hipStream_t stream) {
    const float* x   = (const float*)d_in[0];
    const int*   ei  = (const int*)d_in[1];
    const int*   bat = (const int*)d_in[2];
    const float* W1  = (const float*)d_in[3];
    const float* b1  = (const float*)d_in[4];
    const float* W2  = (const float*)d_in[5];
    const float* b2  = (const float*)d_in[6];
    const float* Wf  = (const float*)d_in[7];
    const float* bf  = (const float*)d_in[8];
    float* out = (float*)d_out;

    const int N = in_sizes[0] / 128;
    const int E = in_sizes[1] / 2;
    const int M = out_size / 128;
    const int* src = ei;
    const int* dst = ei + E;

    char* ws = (char*)d_ws;
    const size_t featb = (size_t)N * 128 * 2;   // bf16 feature plane
    size_t off = 0;
    unsigned short* A   = (unsigned short*)(ws + off); off += (featb + 15) & ~15ull;
    unsigned short* B   = (unsigned short*)(ws + off); off += (featb + 15) & ~15ull;
    float* dis          = (float*)(ws + off); off += (((size_t)N * 4) + 15) & ~15ull;
    int*   counts       = (int*)  (ws + off); off += (((size_t)N * 4) + 15) & ~15ull;
    int*   rowStart     = (int*)  (ws + off); off += (((size_t)(N + 1) * 4) + 15) & ~15ull;
    int*   eidx         = (int*)  (ws + off); off += (((size_t)E * 4) + 15) & ~15ull;
    int*   chunkSum     = (int*)  (ws + off); off += 256 * 4;
    int*   chunkOff     = (int*)  (ws + off); off += 256 * 4;
    unsigned short* Wt1 = (unsigned short*)(ws + off); off += 128 * 128 * 2;
    unsigned short* Wt2 = (unsigned short*)(ws + off); off += 128 * 128 * 2;

    const int nChunks = (N + CHUNK - 1) / CHUNK;
    const int nTiles = (N + 63) / 64;
    const int gemm_grid = nTiles < GEMM_GRID ? nTiles : GEMM_GRID;
    const int gather_blocks = (N + 15) / 16;

    // 1. histogram
    hipMemsetAsync(counts, 0, (size_t)N * sizeof(int), stream);
    k_hist<<<(E + 255) / 256, 256, 0, stream>>>(dst, counts, E);

    // 2. CSR build (+ dis fused into scanwrite)
    k_blocksum<<<nChunks, 256, 0, stream>>>(counts, chunkSum, N);
    k_scanchunks<<<1, 256, 0, stream>>>(chunkSum, chunkOff, rowStart, nChunks, N, E);
    k_scanwrite<<<nChunks, 256, 0, stream>>>(counts, chunkOff, rowStart, counts, dis, N);
    k_place<<<(E + 255) / 256, 256, 0, stream>>>(src, dst, counts, eidx, E);

    // 3. both W transposes (bf16), one launch
    k_prepw2<<<128, 256, 0, stream>>>(W1, W2, Wt1, Wt2);

    // 4. A = x @ W1
    k_gemm_mfma<false><<<gemm_grid, 256, 0, stream>>>(x, Wt1, A, N, nTiles);

    // 5. B = relu(gather(A) + b1)
    k_gather<<<gather_blocks, 256, 0, stream>>>(A, dis, rowStart, eidx, b1, B, N, gather_blocks);

    // 6. A = B @ W2
    k_gemm_mfma<true><<<gemm_grid, 256, 0, stream>>>(B, Wt2, A, N, nTiles);

    // 7. B = relu(gather(A) + b2)
    k_gather<<<gather_blocks, 256, 0, stream>>>(A, dis, rowStart, eidx, b2, B, N, gather_blocks);

    // 8. out = segmean(B) @ Wf + bf
    k_poolhead<<<M, 128, 0, stream>>>(B, bat, Wf, bf, out, N);
}